// Round 2
// baseline (367.960 us; speedup 1.0000x reference)
//
#include <hip/hip_runtime.h>
#include <math.h>

#define NROWS 16      // B*QL
#define NCOLS 6144    // q 4096 | k 1024 | v 1024
#define HID   4096
#define NKV   8
#define HD    128
#define PRIOR 4096
#define NCH   32      // KV chunks in attention kernel
#define CHUNK 128     // keys per chunk
#define SUB   64      // keys per subtile
#define KC1   128     // K-chunk for projection kernels
#define NKC   32      // 4096 / KC1

// ---------------------------------------------------------------------------
// K1: fused QKV projection, split-K partials.  part[NKC][16][6144]
// grid (24, 32) x 256; 1 output col/thread; activation chunk staged in LDS
// (broadcast b128 reads -> no per-thread global broadcast storm).
// ---------------------------------------------------------------------------
__global__ __launch_bounds__(256)
void k_qkv_partial(const float* __restrict__ hid,
                   const float* __restrict__ wq,
                   const float* __restrict__ wk,
                   const float* __restrict__ wv,
                   float* __restrict__ part)
{
    const int t   = threadIdx.x;
    const int col = blockIdx.x * 256 + t;   // 256-col tiles keep weight choice block-uniform
    const int kc  = blockIdx.y;
    const int k0  = kc * KC1;
    __shared__ float sA[NROWS][KC1];
    for (int i = t; i < NROWS * KC1; i += 256) {
        const int r = i >> 7, kk = i & 127;
        sA[r][kk] = hid[(size_t)r * HID + k0 + kk];
    }
    const float* w; int wn, wcol;
    if (col < 4096)      { w = wq; wn = 4096; wcol = col; }
    else if (col < 5120) { w = wk; wn = 1024; wcol = col - 4096; }
    else                 { w = wv; wn = 1024; wcol = col - 5120; }
    const float* wp = w + wcol + (size_t)k0 * wn;
    __syncthreads();

    float acc[NROWS];
#pragma unroll
    for (int m = 0; m < NROWS; m++) acc[m] = 0.f;
#pragma unroll 2
    for (int kk = 0; kk < KC1; kk += 4) {
        const float w0 = wp[(size_t)(kk + 0) * wn];
        const float w1 = wp[(size_t)(kk + 1) * wn];
        const float w2 = wp[(size_t)(kk + 2) * wn];
        const float w3 = wp[(size_t)(kk + 3) * wn];
#pragma unroll
        for (int m = 0; m < NROWS; m++) {
            const float4 h4 = *(const float4*)(&sA[m][kk]);
            acc[m] = fmaf(h4.x, w0, fmaf(h4.y, w1, fmaf(h4.z, w2, fmaf(h4.w, w3, acc[m]))));
        }
    }
    float* po = part + (size_t)kc * (NROWS * NCOLS) + col;
#pragma unroll
    for (int m = 0; m < NROWS; m++) po[(size_t)m * NCOLS] = acc[m];
}

// ---------------------------------------------------------------------------
// K2: reduce split-K partials + RoPE (q scaled by 1/sqrt(HD)).
// ---------------------------------------------------------------------------
__global__ __launch_bounds__(256)
void k_reduce_rope(const float* __restrict__ part, float* __restrict__ qkv)
{
    const int tid = blockIdx.x * 256 + threadIdx.x;
    const double L64 = 0.21586735246819178;   // ln(1e6)/64

    if (tid < 32768) {                         // ---- q pairs ----
        const int d = tid & 63, h = (tid >> 6) & 31, r = tid >> 11;
        const int c1 = h * HD + d;
        float s1 = 0.f, s2 = 0.f;
        for (int c = 0; c < NKC; c++) {
            const float* p = part + (size_t)c * (NROWS * NCOLS) + r * NCOLS + c1;
            s1 += p[0]; s2 += p[64];
        }
        const double ang = (double)(PRIOR + (r & 3)) * exp(-(double)d * L64);
        double sv, cv; sincos(ang, &sv, &cv);
        const float cf = (float)cv, sf = (float)sv, sc = 0.08838834764831845f;
        qkv[r * NCOLS + c1]      = (s1 * cf - s2 * sf) * sc;
        qkv[r * NCOLS + c1 + 64] = (s2 * cf + s1 * sf) * sc;
    } else if (tid < 40960) {                  // ---- k_active pairs ----
        const int idx = tid - 32768;
        const int d = idx & 63, kh = (idx >> 6) & 7, r = idx >> 9;
        const int c1 = 4096 + kh * HD + d;
        float s1 = 0.f, s2 = 0.f;
        for (int c = 0; c < NKC; c++) {
            const float* p = part + (size_t)c * (NROWS * NCOLS) + r * NCOLS + c1;
            s1 += p[0]; s2 += p[64];
        }
        const double ang = (double)(PRIOR + (r & 3)) * exp(-(double)d * L64);
        double sv, cv; sincos(ang, &sv, &cv);
        const float cf = (float)cv, sf = (float)sv;
        qkv[r * NCOLS + c1]      = s1 * cf - s2 * sf;
        qkv[r * NCOLS + c1 + 64] = s2 * cf + s1 * sf;
    } else {                                   // ---- v_active ----
        const int idx = tid - 40960;
        const int n = idx & 1023, r = idx >> 10;
        const int c1 = 5120 + n;
        float s = 0.f;
        for (int c = 0; c < NKC; c++)
            s += part[(size_t)c * (NROWS * NCOLS) + r * NCOLS + c1];
        qkv[r * NCOLS + c1] = s;
    }
}

// ---------------------------------------------------------------------------
// K3: flash-decoding over prior KV.  grid (NCH=32, NKV, B) = 1024 blocks.
// Wave qg privately owns rows qg*4..+3 (key = lane): softmax m/l in regs,
// no cross-wave score reduction.  LDS 38 KB -> 4 blocks/CU, 16 waves/CU.
// Row index r = g*4 + ql.
// ---------------------------------------------------------------------------
__global__ __launch_bounds__(256, 4)
void k_attn_prior(const float* __restrict__ qkv,
                  const float* __restrict__ pk,
                  const float* __restrict__ pv,
                  float* __restrict__ part3)
{
    const int chunk = blockIdx.x, kvh = blockIdx.y, b = blockIdx.z;
    const int t = threadIdx.x;

    __shared__ float kT[SUB][132];   // K subtile [key][d], +4 pad: b128 reads hit 8-phase floor
    __shared__ float pP[SUB][16];    // probabilities [key][r]  (64 B rows, b128-aligned)
    __shared__ float aS[16];         // per-row alpha for PV rescale

    const int key = t & 63;          // score stage: lane = key
    const int qg  = t >> 6;          // wave id; rows qg*4..qg*4+3
    const int dpv = t & 127;         // PV: d ownership
    const int rh  = t >> 7;          // PV: row half (rows rh*8..+7)

    const size_t kvoff = ((size_t)(b * NKV + kvh) * PRIOR + (size_t)chunk * CHUNK) * HD;
    const float* kbase = pk + kvoff;
    const float* vbase = pv + kvoff;

    const float* qr[4];
#pragma unroll
    for (int i = 0; i < 4; i++)      // q row i of wave qg (broadcast loads, L1/L2-hot)
        qr[i] = qkv + (size_t)(b * 4 + i) * NCOLS + (kvh * 4 + qg) * HD;

    float m_r[4], l_r[4];
#pragma unroll
    for (int i = 0; i < 4; i++) { m_r[i] = -INFINITY; l_r[i] = 0.f; }
    float o[8] = {0.f,0.f,0.f,0.f,0.f,0.f,0.f,0.f};

    for (int st = 0; st < CHUNK / SUB; st++) {
        // ---- stage K subtile, fully coalesced (512 B per 32-lane group) ----
#pragma unroll
        for (int p = 0; p < 8; p++) {
            const int i = p * 256 + t;
            const int kk = i >> 5, dl = (i & 31) * 4;
            const float4 k4 = *(const float4*)(kbase + (size_t)(st * SUB + kk) * HD + dl);
            *(float4*)(&kT[kk][dl]) = k4;
        }
        __syncthreads();
        // ---- scores: thread = (key, 4 rows); q via broadcast global loads ----
        float s0 = 0.f, s1 = 0.f, s2 = 0.f, s3 = 0.f;
#pragma unroll 2
        for (int d = 0; d < HD; d += 4) {
            const float4 k4 = *(const float4*)(&kT[key][d]);
            const float4 qa = *(const float4*)(qr[0] + d);
            const float4 qb = *(const float4*)(qr[1] + d);
            const float4 qc = *(const float4*)(qr[2] + d);
            const float4 qd = *(const float4*)(qr[3] + d);
            s0 = fmaf(qa.x,k4.x, fmaf(qa.y,k4.y, fmaf(qa.z,k4.z, fmaf(qa.w,k4.w, s0))));
            s1 = fmaf(qb.x,k4.x, fmaf(qb.y,k4.y, fmaf(qb.z,k4.z, fmaf(qb.w,k4.w, s1))));
            s2 = fmaf(qc.x,k4.x, fmaf(qc.y,k4.y, fmaf(qc.z,k4.z, fmaf(qc.w,k4.w, s2))));
            s3 = fmaf(qd.x,k4.x, fmaf(qd.y,k4.y, fmaf(qd.z,k4.z, fmaf(qd.w,k4.w, s3))));
        }
        // ---- wave-private online softmax (rows qg*4..+3, all 64 lanes = keys) ----
        float sv[4] = {s0, s1, s2, s3};
        float mx[4] = {s0, s1, s2, s3};
        for (int off = 32; off; off >>= 1) {
#pragma unroll
            for (int i = 0; i < 4; i++) mx[i] = fmaxf(mx[i], __shfl_xor(mx[i], off));
        }
        float pr[4], sm[4], al[4];
#pragma unroll
        for (int i = 0; i < 4; i++) {
            const float mn = fmaxf(m_r[i], mx[i]);
            pr[i] = __expf(sv[i] - mn);
            al[i] = __expf(m_r[i] - mn);     // first subtile: exp(-inf)=0
            m_r[i] = mn;
            sm[i] = pr[i];
        }
        *(float4*)(&pP[key][qg * 4]) = make_float4(pr[0], pr[1], pr[2], pr[3]);
        for (int off = 32; off; off >>= 1) {
#pragma unroll
            for (int i = 0; i < 4; i++) sm[i] += __shfl_xor(sm[i], off);
        }
#pragma unroll
        for (int i = 0; i < 4; i++) l_r[i] = l_r[i] * al[i] + sm[i];
        if (key == 0) {
#pragma unroll
            for (int i = 0; i < 4; i++) aS[qg * 4 + i] = al[i];
        }
        __syncthreads();
        // ---- PV: thread = (d, 8 rows); V coalesced, read 2x (row halves) ----
        float alv[8];
#pragma unroll
        for (int j = 0; j < 8; j++) alv[j] = aS[rh * 8 + j];
#pragma unroll
        for (int j = 0; j < 8; j++) o[j] *= alv[j];
        const float* vs = vbase + (size_t)st * SUB * HD + dpv;
#pragma unroll 8
        for (int k2 = 0; k2 < SUB; k2++) {
            const float v = vs[(size_t)k2 * HD];
            const float4 pa = *(const float4*)(&pP[k2][rh * 8]);
            const float4 pb = *(const float4*)(&pP[k2][rh * 8 + 4]);
            o[0] = fmaf(pa.x, v, o[0]); o[1] = fmaf(pa.y, v, o[1]);
            o[2] = fmaf(pa.z, v, o[2]); o[3] = fmaf(pa.w, v, o[3]);
            o[4] = fmaf(pb.x, v, o[4]); o[5] = fmaf(pb.y, v, o[5]);
            o[6] = fmaf(pb.z, v, o[6]); o[7] = fmaf(pb.w, v, o[7]);
        }
        __syncthreads();
    }
    // ---- write chunk partial: m[16], l[16], o[16][128] ----
    float* pout = part3 + (size_t)((b * NKV + kvh) * NCH + chunk) * 2080;
    if (key == 0) {
#pragma unroll
        for (int i = 0; i < 4; i++) { pout[qg * 4 + i] = m_r[i]; pout[16 + qg * 4 + i] = l_r[i]; }
    }
#pragma unroll
    for (int j = 0; j < 8; j++)
        pout[32 + (rh * 8 + j) * HD + dpv] = o[j];
}

// ---------------------------------------------------------------------------
// K4: combine chunk partials + causal active keys (shared max / divisor).
// grid 128 blocks = (g, kvh, b); each handles 4 rows (fixed head g).
// ---------------------------------------------------------------------------
__global__ __launch_bounds__(256)
void k_combine(const float* __restrict__ qkv,
               const float* __restrict__ part3,
               float* __restrict__ attn)
{
    const int g = blockIdx.x & 3, kvh = (blockIdx.x >> 2) & 7, b = blockIdx.x >> 5;
    const int t = threadIdx.x;
    __shared__ float qL[4][128], kA[4][128], vA[4][128];
    __shared__ float mC[NCH][4], lC[NCH][4], fC[NCH][4];
    __shared__ float sAct[4][4], pA[4][4], invL[4];

    for (int i = t; i < 512; i += 256) {
        const int ql = i >> 7, d = i & 127;
        qL[ql][d] = qkv[(size_t)(b * 4 + ql) * NCOLS + (kvh * 4 + g) * HD + d];
        kA[ql][d] = qkv[(size_t)(b * 4 + ql) * NCOLS + 4096 + kvh * HD + d];
        vA[ql][d] = qkv[(size_t)(b * 4 + ql) * NCOLS + 5120 + kvh * HD + d];
    }
    const float* p3 = part3 + (size_t)(b * NKV + kvh) * NCH * 2080;
    for (int i = t; i < NCH * 4; i += 256) {
        const int c = i >> 2, lr = i & 3;
        mC[c][lr] = p3[c * 2080 + g * 4 + lr];
        lC[c][lr] = p3[c * 2080 + 16 + g * 4 + lr];
    }
    __syncthreads();
    if (t < 16) {                        // active scores (q pre-scaled by 1/sqrt(HD))
        const int lr = t >> 2, k = t & 3;
        float s = 0.f;
        for (int d = 0; d < HD; d++) s = fmaf(qL[lr][d], kA[k][d], s);
        sAct[lr][k] = s;
    }
    __syncthreads();
    if (t < 4) {                         // per-row global stats (lr == ql)
        const int lr = t;
        float M = -INFINITY;
        for (int c = 0; c < NCH; c++) M = fmaxf(M, mC[c][lr]);
        for (int k = 0; k <= lr; k++) M = fmaxf(M, sAct[lr][k]);
        float l = 0.f;
        for (int c = 0; c < NCH; c++) {
            const float f = __expf(mC[c][lr] - M);
            fC[c][lr] = f;
            l = fmaf(f, lC[c][lr], l);
        }
#pragma unroll
        for (int k = 0; k < 4; k++) {
            const float p = (k <= lr) ? __expf(sAct[lr][k] - M) : 0.f;
            pA[lr][k] = p; l += p;
        }
        invL[lr] = 1.f / l;
    }
    __syncthreads();

    const int d = t & 127, hr = t >> 7;
    const int lr0 = hr * 2, lr1 = hr * 2 + 1;
    float o0 = 0.f, o1 = 0.f;
    for (int c = 0; c < NCH; c++) {
        const float f0 = fC[c][lr0], f1 = fC[c][lr1];
        const float* pa = p3 + c * 2080 + 32 + (g * 4 + lr0) * HD + d;
        o0 = fmaf(f0, pa[0],  o0);
        o1 = fmaf(f1, pa[HD], o1);
    }
#pragma unroll
    for (int k = 0; k < 4; k++) {
        const float v = vA[k][d];
        o0 = fmaf(pA[lr0][k], v, o0);
        o1 = fmaf(pA[lr1][k], v, o1);
    }
    attn[(size_t)(b * 4 + lr0) * HID + (kvh * 4 + g) * HD + d] = o0 * invL[lr0];
    attn[(size_t)(b * 4 + lr1) * HID + (kvh * 4 + g) * HD + d] = o1 * invL[lr1];
}

// ---------------------------------------------------------------------------
// K5: output projection split-K partials.  part[NKC][16][4096], grid (16,32).
// ---------------------------------------------------------------------------
__global__ __launch_bounds__(256)
void k_out_partial(const float* __restrict__ attn,
                   const float* __restrict__ wo,
                   float* __restrict__ part)
{
    const int t = threadIdx.x;
    const int col = blockIdx.x * 256 + t;
    const int kc = blockIdx.y;
    const int k0 = kc * KC1;
    __shared__ float sA[NROWS][KC1];
    for (int i = t; i < NROWS * KC1; i += 256) {
        const int r = i >> 7, kk = i & 127;
        sA[r][kk] = attn[(size_t)r * HID + k0 + kk];
    }
    const float* wp = wo + col + (size_t)k0 * HID;
    __syncthreads();

    float acc[NROWS];
#pragma unroll
    for (int m = 0; m < NROWS; m++) acc[m] = 0.f;
#pragma unroll 2
    for (int kk = 0; kk < KC1; kk += 4) {
        const float w0 = wp[(size_t)(kk + 0) * HID];
        const float w1 = wp[(size_t)(kk + 1) * HID];
        const float w2 = wp[(size_t)(kk + 2) * HID];
        const float w3 = wp[(size_t)(kk + 3) * HID];
#pragma unroll
        for (int m = 0; m < NROWS; m++) {
            const float4 h4 = *(const float4*)(&sA[m][kk]);
            acc[m] = fmaf(h4.x, w0, fmaf(h4.y, w1, fmaf(h4.z, w2, fmaf(h4.w, w3, acc[m]))));
        }
    }
    float* po = part + (size_t)kc * (NROWS * HID) + col;
#pragma unroll
    for (int m = 0; m < NROWS; m++) po[(size_t)m * HID] = acc[m];
}

// K5b: reduce out-proj partials -> d_out (float4)
__global__ __launch_bounds__(256)
void k_out_reduce(const float* __restrict__ part, float* __restrict__ out)
{
    const int tid = blockIdx.x * 256 + threadIdx.x;   // 16384
    const float* p = part + (size_t)tid * 4;
    float4 s = make_float4(0.f, 0.f, 0.f, 0.f);
    for (int c = 0; c < NKC; c++) {
        const float4 a = *(const float4*)(p + (size_t)c * (NROWS * HID));
        s.x += a.x; s.y += a.y; s.z += a.z; s.w += a.w;
    }
    *(float4*)(out + (size_t)tid * 4) = s;
}

// ---------------------------------------------------------------------------
extern "C" void kernel_launch(void* const* d_in, const int* in_sizes, int n_in,
                              void* d_out, int out_size, void* d_ws, size_t ws_size,
                              hipStream_t stream)
{
    (void)in_sizes; (void)n_in; (void)out_size; (void)ws_size;
    const float* hid = (const float*)d_in[0];
    const float* pk  = (const float*)d_in[1];
    const float* pv  = (const float*)d_in[2];
    const float* wq  = (const float*)d_in[3];
    const float* wk  = (const float*)d_in[4];
    const float* wv  = (const float*)d_in[5];
    const float* wo  = (const float*)d_in[6];
    float* out = (float*)d_out;
    float* ws  = (float*)d_ws;

    // workspace (floats); sequential lifetimes share region 0:
    //   P1 [k1->k2] 3,145,728 | P3 [k3->k4] 2,129,920 | P5 [k5->k5b] 2,097,152
    float* P1   = ws;
    float* P3   = ws;
    float* P5   = ws;
    float* qkv  = ws + 3145728;            // 98,304
    float* attn = ws + 3244032;            // 65,536   (total 13.24 MB)

    k_qkv_partial<<<dim3(24, NKC), 256, 0, stream>>>(hid, wq, wk, wv, P1);
    k_reduce_rope<<<224, 256, 0, stream>>>(P1, qkv);
    k_attn_prior<<<dim3(NCH, NKV, 4), 256, 0, stream>>>(qkv, pk, pv, P3);
    k_combine<<<128, 256, 0, stream>>>(qkv, P3, attn);
    k_out_partial<<<dim3(16, NKC), 256, 0, stream>>>(attn, wo, P5);
    k_out_reduce<<<64, 256, 0, stream>>>(P5, out);
}

// Round 3
// 321.456 us; speedup vs baseline: 1.1447x; 1.1447x over previous
//
#include <hip/hip_runtime.h>
#include <math.h>

#define NROWS 16      // B*QL
#define NCOLS 6144    // q 4096 | k 1024 | v 1024
#define HID   4096
#define NKV   8
#define HD    128
#define PRIOR 4096
#define NCH   32      // KV chunks in attention kernel
#define CHUNK 128     // keys per chunk
#define SUB   64      // keys per subtile
#define KC1   128     // K-chunk for projection kernels
#define NKC   32      // 4096 / KC1

// ---------------------------------------------------------------------------
// K1: fused QKV projection, split-K partials.  part[NKC][16][6144]
// grid (24, 32) x 128 threads (3 blocks/CU even); 2 cols/thread, float2
// weight loads; activations via block-uniform loads (s_load path).
// ---------------------------------------------------------------------------
__global__ __launch_bounds__(128)
void k_qkv_partial(const float* __restrict__ hid,
                   const float* __restrict__ wq,
                   const float* __restrict__ wk,
                   const float* __restrict__ wv,
                   float* __restrict__ part)
{
    const int t   = threadIdx.x;
    const int col = blockIdx.x * 256 + t * 2;   // 256-col tiles: weight choice block-uniform
    const int kc  = blockIdx.y;
    const int k0  = kc * KC1;
    const float* w; int wn, wcol;
    if (col < 4096)      { w = wq; wn = 4096; wcol = col; }
    else if (col < 5120) { w = wk; wn = 1024; wcol = col - 4096; }
    else                 { w = wv; wn = 1024; wcol = col - 5120; }
    const float* wp = w + wcol + (size_t)k0 * wn;

    float acc[NROWS][2];
#pragma unroll
    for (int m = 0; m < NROWS; m++) { acc[m][0] = 0.f; acc[m][1] = 0.f; }
#pragma unroll 2
    for (int kk = 0; kk < KC1; kk += 4) {
        const float2 w0 = *(const float2*)(wp + (size_t)(kk + 0) * wn);
        const float2 w1 = *(const float2*)(wp + (size_t)(kk + 1) * wn);
        const float2 w2 = *(const float2*)(wp + (size_t)(kk + 2) * wn);
        const float2 w3 = *(const float2*)(wp + (size_t)(kk + 3) * wn);
#pragma unroll
        for (int m = 0; m < NROWS; m++) {
            const float4 h4 = *(const float4*)(hid + (size_t)m * HID + k0 + kk);
            acc[m][0] = fmaf(h4.x, w0.x, fmaf(h4.y, w1.x, fmaf(h4.z, w2.x, fmaf(h4.w, w3.x, acc[m][0]))));
            acc[m][1] = fmaf(h4.x, w0.y, fmaf(h4.y, w1.y, fmaf(h4.z, w2.y, fmaf(h4.w, w3.y, acc[m][1]))));
        }
    }
    float* po = part + (size_t)kc * (NROWS * NCOLS) + col;
#pragma unroll
    for (int m = 0; m < NROWS; m++)
        *(float2*)(po + (size_t)m * NCOLS) = make_float2(acc[m][0], acc[m][1]);
}

// ---------------------------------------------------------------------------
// K2: reduce split-K partials + RoPE (q scaled by 1/sqrt(HD)).
// ---------------------------------------------------------------------------
__global__ __launch_bounds__(256)
void k_reduce_rope(const float* __restrict__ part, float* __restrict__ qkv)
{
    const int tid = blockIdx.x * 256 + threadIdx.x;
    const double L64 = 0.21586735246819178;   // ln(1e6)/64

    if (tid < 32768) {                         // ---- q pairs ----
        const int d = tid & 63, h = (tid >> 6) & 31, r = tid >> 11;
        const int c1 = h * HD + d;
        float s1 = 0.f, s2 = 0.f;
        for (int c = 0; c < NKC; c++) {
            const float* p = part + (size_t)c * (NROWS * NCOLS) + r * NCOLS + c1;
            s1 += p[0]; s2 += p[64];
        }
        const double ang = (double)(PRIOR + (r & 3)) * exp(-(double)d * L64);
        double sv, cv; sincos(ang, &sv, &cv);
        const float cf = (float)cv, sf = (float)sv, sc = 0.08838834764831845f;
        qkv[r * NCOLS + c1]      = (s1 * cf - s2 * sf) * sc;
        qkv[r * NCOLS + c1 + 64] = (s2 * cf + s1 * sf) * sc;
    } else if (tid < 40960) {                  // ---- k_active pairs ----
        const int idx = tid - 32768;
        const int d = idx & 63, kh = (idx >> 6) & 7, r = idx >> 9;
        const int c1 = 4096 + kh * HD + d;
        float s1 = 0.f, s2 = 0.f;
        for (int c = 0; c < NKC; c++) {
            const float* p = part + (size_t)c * (NROWS * NCOLS) + r * NCOLS + c1;
            s1 += p[0]; s2 += p[64];
        }
        const double ang = (double)(PRIOR + (r & 3)) * exp(-(double)d * L64);
        double sv, cv; sincos(ang, &sv, &cv);
        const float cf = (float)cv, sf = (float)sv;
        qkv[r * NCOLS + c1]      = s1 * cf - s2 * sf;
        qkv[r * NCOLS + c1 + 64] = s2 * cf + s1 * sf;
    } else {                                   // ---- v_active ----
        const int idx = tid - 40960;
        const int n = idx & 1023, r = idx >> 10;
        const int c1 = 5120 + n;
        float s = 0.f;
        for (int c = 0; c < NKC; c++)
            s += part[(size_t)c * (NROWS * NCOLS) + r * NCOLS + c1];
        qkv[r * NCOLS + c1] = s;
    }
}

// ---------------------------------------------------------------------------
// K3: flash-decoding over prior KV.  grid (32, 8, 4) = 1024 blocks = 4/CU.
// LDS exactly 40 KB (kT 32K with pP/aS aliased into its tail + qT 8K).
// Score: 4x4 tile, d-quarter = lane bits 4-5 -> shfl_xor(16/32) reduce;
// softmax wave-private (m/l in regs).  PV: key-partitioned, b128 V loads.
// ---------------------------------------------------------------------------
__global__ __launch_bounds__(256, 4)
void k_attn_prior(const float* __restrict__ qkv,
                  const float* __restrict__ pk,
                  const float* __restrict__ pv,
                  float* __restrict__ part3)
{
    const int chunk = blockIdx.x, kvh = blockIdx.y, b = blockIdx.z;
    const int t = threadIdx.x;
    const int lane = t & 63;

    __shared__ float kT[128][64];   // [d][key] 32 KB (stride 64: 2-way = free)
    __shared__ float qT[128][16];   // [d][row]  8 KB (broadcast reads)
    // aliases into kT (dead regions at time of use; barriers order them):
    float* pP = &kT[88][0];         // probs [key][20] pad, 5120 B @ byte 22528
    float* aS = &kT[108][0];        // alpha[16], 64 B @ byte 27648

    const int qt = t >> 6;          // wave id = row group (rows qt*4..+3)
    const int h  = (lane >> 4) & 3; // d-quarter (lane subfield!)
    const int kt = lane & 15;       // key group (keys kt*4..+3)

    const int d4pv = t & 31;        // PV: d = d4pv*4..+3
    const int kp   = (t >> 5) & 3;  // PV: key partition (keys kp*16..+15)
    const int rh   = t >> 7;        // PV: row half (rows rh*8..+7)

    const size_t kvoff = ((size_t)(b * NKV + kvh) * PRIOR + (size_t)chunk * CHUNK) * HD;
    const float* kbase = pk + kvoff;
    const float* vbase = pv + kvoff;

    // stage Q transposed (once)
    for (int i = t; i < 2048; i += 256) {
        const int r = i & 15, d = i >> 4;
        const int ql = r & 3, g = r >> 2;
        qT[d][r] = qkv[(size_t)(b * 4 + ql) * NCOLS + (kvh * 4 + g) * HD + d];
    }

    float m_r[4], l_r[4];
#pragma unroll
    for (int i = 0; i < 4; i++) { m_r[i] = -INFINITY; l_r[i] = 0.f; }
    float o[8][4];
#pragma unroll
    for (int jr = 0; jr < 8; jr++)
#pragma unroll
        for (int jd = 0; jd < 4; jd++) o[jr][jd] = 0.f;

    for (int st = 0; st < CHUNK / SUB; st++) {
        // ---- stage K^T: lane = key, wave qt covers d-range qt*32..+31 ----
        {
            const float* kr = kbase + (size_t)(st * SUB + lane) * HD + qt * 32;
#pragma unroll
            for (int i = 0; i < 8; i++) {
                const float4 k4 = *(const float4*)(kr + i * 4);
                const int d = qt * 32 + i * 4;
                kT[d + 0][lane] = k4.x; kT[d + 1][lane] = k4.y;
                kT[d + 2][lane] = k4.z; kT[d + 3][lane] = k4.w;
            }
        }
        __syncthreads();   // bar-a: kT (and qT, first iter) ready

        // ---- scores: 4 rows x 4 keys per thread, d-quarter h ----
        float a[4][4];
#pragma unroll
        for (int i = 0; i < 4; i++)
#pragma unroll
            for (int j = 0; j < 4; j++) a[i][j] = 0.f;
#pragma unroll 4
        for (int dd = 0; dd < 32; dd++) {
            const int d = h * 32 + dd;
            const float4 q4 = *(const float4*)(&qT[d][qt * 4]);
            const float4 k4 = *(const float4*)(&kT[d][kt * 4]);
            a[0][0]=fmaf(q4.x,k4.x,a[0][0]); a[0][1]=fmaf(q4.x,k4.y,a[0][1]); a[0][2]=fmaf(q4.x,k4.z,a[0][2]); a[0][3]=fmaf(q4.x,k4.w,a[0][3]);
            a[1][0]=fmaf(q4.y,k4.x,a[1][0]); a[1][1]=fmaf(q4.y,k4.y,a[1][1]); a[1][2]=fmaf(q4.y,k4.z,a[1][2]); a[1][3]=fmaf(q4.y,k4.w,a[1][3]);
            a[2][0]=fmaf(q4.z,k4.x,a[2][0]); a[2][1]=fmaf(q4.z,k4.y,a[2][1]); a[2][2]=fmaf(q4.z,k4.z,a[2][2]); a[2][3]=fmaf(q4.z,k4.w,a[2][3]);
            a[3][0]=fmaf(q4.w,k4.x,a[3][0]); a[3][1]=fmaf(q4.w,k4.y,a[3][1]); a[3][2]=fmaf(q4.w,k4.z,a[3][2]); a[3][3]=fmaf(q4.w,k4.w,a[3][3]);
        }
        __syncthreads();   // bar-b: kT reads done (pP aliases kT rows 88..108)

        // ---- reduce d-quarters via xor shuffles (lanes ^16, ^32) ----
#pragma unroll
        for (int i = 0; i < 4; i++)
#pragma unroll
            for (int j = 0; j < 4; j++) {
                float v = a[i][j];
                v += __shfl_xor(v, 16);
                v += __shfl_xor(v, 32);
                a[i][j] = v;
            }
        // ---- wave-private online softmax ----
        float al[4], pr[4][4];
#pragma unroll
        for (int i = 0; i < 4; i++) {
            float mx = fmaxf(fmaxf(a[i][0], a[i][1]), fmaxf(a[i][2], a[i][3]));
            mx = fmaxf(mx, __shfl_xor(mx, 1));
            mx = fmaxf(mx, __shfl_xor(mx, 2));
            mx = fmaxf(mx, __shfl_xor(mx, 4));
            mx = fmaxf(mx, __shfl_xor(mx, 8));
            const float mn = fmaxf(m_r[i], mx);
            al[i] = __expf(m_r[i] - mn);      // first subtile: exp(-inf)=0
            m_r[i] = mn;
            float s = 0.f;
#pragma unroll
            for (int j = 0; j < 4; j++) { pr[i][j] = __expf(a[i][j] - mn); s += pr[i][j]; }
            s += __shfl_xor(s, 1); s += __shfl_xor(s, 2);
            s += __shfl_xor(s, 4); s += __shfl_xor(s, 8);
            l_r[i] = l_r[i] * al[i] + s;
        }
        if (h == 0) {                         // one d-copy writes probs
#pragma unroll
            for (int j = 0; j < 4; j++)
                *(float4*)(pP + (kt * 4 + j) * 20 + qt * 4) =
                    make_float4(pr[0][j], pr[1][j], pr[2][j], pr[3][j]);
        }
        if (lane == 0) {
#pragma unroll
            for (int i = 0; i < 4; i++) aS[qt * 4 + i] = al[i];
        }
        __syncthreads();   // bar-c: pP/aS visible

        // ---- PV: thread = (d4, key-partition, row-half); V b128 coalesced ----
        {
            float alv[8];
#pragma unroll
            for (int jr = 0; jr < 8; jr++) alv[jr] = aS[rh * 8 + jr];
#pragma unroll
            for (int jr = 0; jr < 8; jr++)
#pragma unroll
                for (int jd = 0; jd < 4; jd++) o[jr][jd] *= alv[jr];
            const float* vs = vbase + (size_t)st * SUB * HD + d4pv * 4;
#pragma unroll 4
            for (int j = 0; j < 16; j++) {
                const int key = kp * 16 + j;
                const float4 v4 = *(const float4*)(vs + (size_t)key * HD);
                const float4 pa = *(const float4*)(pP + key * 20 + rh * 8);
                const float4 pb = *(const float4*)(pP + key * 20 + rh * 8 + 4);
                const float pv8[8] = {pa.x, pa.y, pa.z, pa.w, pb.x, pb.y, pb.z, pb.w};
                const float vv[4] = {v4.x, v4.y, v4.z, v4.w};
#pragma unroll
                for (int jr = 0; jr < 8; jr++)
#pragma unroll
                    for (int jd = 0; jd < 4; jd++)
                        o[jr][jd] = fmaf(pv8[jr], vv[jd], o[jr][jd]);
            }
        }
        __syncthreads();   // bar-d: pP reads done before next staging
    }

    // ---- reduce kp partitions through dead kT (stride 36: aligned, low-conflict) ----
    float* red = &kT[0][0];
    const int rb = (rh * 32 + d4pv) * 36;
    if (kp >= 2) {
        float* wdst = red + (kp - 2) * 2304 + rb;
#pragma unroll
        for (int jr = 0; jr < 8; jr++)
            *(float4*)(wdst + jr * 4) = make_float4(o[jr][0], o[jr][1], o[jr][2], o[jr][3]);
    }
    __syncthreads();
    if (kp < 2) {
        const float* rsrc = red + kp * 2304 + rb;
#pragma unroll
        for (int jr = 0; jr < 8; jr++) {
            const float4 x = *(const float4*)(rsrc + jr * 4);
            o[jr][0] += x.x; o[jr][1] += x.y; o[jr][2] += x.z; o[jr][3] += x.w;
        }
    }
    __syncthreads();
    if (kp == 1) {
        float* wdst = red + rb;
#pragma unroll
        for (int jr = 0; jr < 8; jr++)
            *(float4*)(wdst + jr * 4) = make_float4(o[jr][0], o[jr][1], o[jr][2], o[jr][3]);
    }
    __syncthreads();

    float* pout = part3 + (size_t)((b * NKV + kvh) * NCH + chunk) * 2080;
    if (lane == 0) {
#pragma unroll
        for (int i = 0; i < 4; i++) { pout[qt * 4 + i] = m_r[i]; pout[16 + qt * 4 + i] = l_r[i]; }
    }
    if (kp == 0) {
        const float* rsrc = red + rb;
#pragma unroll
        for (int jr = 0; jr < 8; jr++) {
            const float4 x = *(const float4*)(rsrc + jr * 4);
            *(float4*)(pout + 32 + (size_t)(rh * 8 + jr) * HD + d4pv * 4) =
                make_float4(o[jr][0] + x.x, o[jr][1] + x.y, o[jr][2] + x.z, o[jr][3] + x.w);
        }
    }
}

// ---------------------------------------------------------------------------
// K4: combine chunk partials + causal active keys (shared max / divisor).
// grid 128 blocks = (g, kvh, b); each handles 4 rows (fixed head g).
// ---------------------------------------------------------------------------
__global__ __launch_bounds__(256)
void k_combine(const float* __restrict__ qkv,
               const float* __restrict__ part3,
               float* __restrict__ attn)
{
    const int g = blockIdx.x & 3, kvh = (blockIdx.x >> 2) & 7, b = blockIdx.x >> 5;
    const int t = threadIdx.x;
    __shared__ float qL[4][128], kA[4][128], vA[4][128];
    __shared__ float mC[NCH][4], lC[NCH][4], fC[NCH][4];
    __shared__ float sAct[4][4], pA[4][4], invL[4];

    for (int i = t; i < 512; i += 256) {
        const int ql = i >> 7, d = i & 127;
        qL[ql][d] = qkv[(size_t)(b * 4 + ql) * NCOLS + (kvh * 4 + g) * HD + d];
        kA[ql][d] = qkv[(size_t)(b * 4 + ql) * NCOLS + 4096 + kvh * HD + d];
        vA[ql][d] = qkv[(size_t)(b * 4 + ql) * NCOLS + 5120 + kvh * HD + d];
    }
    const float* p3 = part3 + (size_t)(b * NKV + kvh) * NCH * 2080;
    for (int i = t; i < NCH * 4; i += 256) {
        const int c = i >> 2, lr = i & 3;
        mC[c][lr] = p3[c * 2080 + g * 4 + lr];
        lC[c][lr] = p3[c * 2080 + 16 + g * 4 + lr];
    }
    __syncthreads();
    if (t < 16) {                        // active scores (q pre-scaled by 1/sqrt(HD))
        const int lr = t >> 2, k = t & 3;
        float s = 0.f;
        for (int d = 0; d < HD; d++) s = fmaf(qL[lr][d], kA[k][d], s);
        sAct[lr][k] = s;
    }
    __syncthreads();
    if (t < 4) {                         // per-row global stats (lr == ql)
        const int lr = t;
        float M = -INFINITY;
        for (int c = 0; c < NCH; c++) M = fmaxf(M, mC[c][lr]);
        for (int k = 0; k <= lr; k++) M = fmaxf(M, sAct[lr][k]);
        float l = 0.f;
        for (int c = 0; c < NCH; c++) {
            const float f = __expf(mC[c][lr] - M);
            fC[c][lr] = f;
            l = fmaf(f, lC[c][lr], l);
        }
#pragma unroll
        for (int k = 0; k < 4; k++) {
            const float p = (k <= lr) ? __expf(sAct[lr][k] - M) : 0.f;
            pA[lr][k] = p; l += p;
        }
        invL[lr] = 1.f / l;
    }
    __syncthreads();

    const int d = t & 127, hr = t >> 7;
    const int lr0 = hr * 2, lr1 = hr * 2 + 1;
    float o0 = 0.f, o1 = 0.f;
    for (int c = 0; c < NCH; c++) {
        const float f0 = fC[c][lr0], f1 = fC[c][lr1];
        const float* pa = p3 + c * 2080 + 32 + (g * 4 + lr0) * HD + d;
        o0 = fmaf(f0, pa[0],  o0);
        o1 = fmaf(f1, pa[HD], o1);
    }
#pragma unroll
    for (int k = 0; k < 4; k++) {
        const float v = vA[k][d];
        o0 = fmaf(pA[lr0][k], v, o0);
        o1 = fmaf(pA[lr1][k], v, o1);
    }
    attn[(size_t)(b * 4 + lr0) * HID + (kvh * 4 + g) * HD + d] = o0 * invL[lr0];
    attn[(size_t)(b * 4 + lr1) * HID + (kvh * 4 + g) * HD + d] = o1 * invL[lr1];
}

// ---------------------------------------------------------------------------
// K5: output projection split-K partials.  part[NKC][16][4096], grid (16,32)x128.
// ---------------------------------------------------------------------------
__global__ __launch_bounds__(128)
void k_out_partial(const float* __restrict__ attn,
                   const float* __restrict__ wo,
                   float* __restrict__ part)
{
    const int t = threadIdx.x;
    const int col = blockIdx.x * 256 + t * 2;
    const int kc = blockIdx.y;
    const int k0 = kc * KC1;
    const float* wp = wo + col + (size_t)k0 * HID;

    float acc[NROWS][2];
#pragma unroll
    for (int m = 0; m < NROWS; m++) { acc[m][0] = 0.f; acc[m][1] = 0.f; }
#pragma unroll 2
    for (int kk = 0; kk < KC1; kk += 4) {
        const float2 w0 = *(const float2*)(wp + (size_t)(kk + 0) * HID);
        const float2 w1 = *(const float2*)(wp + (size_t)(kk + 1) * HID);
        const float2 w2 = *(const float2*)(wp + (size_t)(kk + 2) * HID);
        const float2 w3 = *(const float2*)(wp + (size_t)(kk + 3) * HID);
#pragma unroll
        for (int m = 0; m < NROWS; m++) {
            const float4 h4 = *(const float4*)(attn + (size_t)m * HID + k0 + kk);
            acc[m][0] = fmaf(h4.x, w0.x, fmaf(h4.y, w1.x, fmaf(h4.z, w2.x, fmaf(h4.w, w3.x, acc[m][0]))));
            acc[m][1] = fmaf(h4.x, w0.y, fmaf(h4.y, w1.y, fmaf(h4.z, w2.y, fmaf(h4.w, w3.y, acc[m][1]))));
        }
    }
    float* po = part + (size_t)kc * (NROWS * HID) + col;
#pragma unroll
    for (int m = 0; m < NROWS; m++)
        *(float2*)(po + (size_t)m * HID) = make_float2(acc[m][0], acc[m][1]);
}

// K5b: reduce out-proj partials -> d_out (float4)
__global__ __launch_bounds__(256)
void k_out_reduce(const float* __restrict__ part, float* __restrict__ out)
{
    const int tid = blockIdx.x * 256 + threadIdx.x;   // 16384
    const float* p = part + (size_t)tid * 4;
    float4 s = make_float4(0.f, 0.f, 0.f, 0.f);
    for (int c = 0; c < NKC; c++) {
        const float4 a = *(const float4*)(p + (size_t)c * (NROWS * HID));
        s.x += a.x; s.y += a.y; s.z += a.z; s.w += a.w;
    }
    *(float4*)(out + (size_t)tid * 4) = s;
}

// ---------------------------------------------------------------------------
extern "C" void kernel_launch(void* const* d_in, const int* in_sizes, int n_in,
                              void* d_out, int out_size, void* d_ws, size_t ws_size,
                              hipStream_t stream)
{
    (void)in_sizes; (void)n_in; (void)out_size; (void)ws_size;
    const float* hid = (const float*)d_in[0];
    const float* pk  = (const float*)d_in[1];
    const float* pv  = (const float*)d_in[2];
    const float* wq  = (const float*)d_in[3];
    const float* wk  = (const float*)d_in[4];
    const float* wv  = (const float*)d_in[5];
    const float* wo  = (const float*)d_in[6];
    float* out = (float*)d_out;
    float* ws  = (float*)d_ws;

    // workspace (floats); sequential lifetimes share region 0:
    //   P1 [k1->k2] 3,145,728 | P3 [k3->k4] 2,129,920 | P5 [k5->k5b] 2,097,152
    float* P1   = ws;
    float* P3   = ws;
    float* P5   = ws;
    float* qkv  = ws + 3145728;            // 98,304
    float* attn = ws + 3244032;            // 65,536   (total 13.24 MB)

    k_qkv_partial<<<dim3(24, NKC), 128, 0, stream>>>(hid, wq, wk, wv, P1);
    k_reduce_rope<<<224, 256, 0, stream>>>(P1, qkv);
    k_attn_prior<<<dim3(NCH, NKV, 4), 256, 0, stream>>>(qkv, pk, pv, P3);
    k_combine<<<128, 256, 0, stream>>>(qkv, P3, attn);
    k_out_partial<<<dim3(16, NKC), 128, 0, stream>>>(attn, wo, P5);
    k_out_reduce<<<64, 256, 0, stream>>>(P5, out);
}